// Round 12
// baseline (510.691 us; speedup 1.0000x reference)
//
#include <hip/hip_runtime.h>
#include <math.h>

#define NN 100000
#define NE 1600000
#define LAYERS 3
#define NEG 0.2f
#define BN_EPS 1e-5f
#define LOG2E 1.4426950408889634f

#define NB 196            // buckets = ceil(NN / 512)
#define NWG 512           // multisplit workgroups
#define CHUNK 3125        // NE / NWG exactly
#define MOMB 304          // moments blocks
#define TFB 1563          // tf blocks = ceil(NN/64)
#define ETB 6250          // edgetf blocks = NN/16 exactly

typedef __attribute__((ext_vector_type(8))) short bf16x8;
typedef __attribute__((ext_vector_type(4))) float f32x4;

#if __has_builtin(__builtin_amdgcn_exp2f)
#define EXP2(x) __builtin_amdgcn_exp2f(x)
#else
#define EXP2(x) __expf((x) * 0.6931471805599453f)
#endif

__device__ __forceinline__ unsigned f2bf(float x) {   // fp32 -> bf16 bits, RNE
    unsigned u = __float_as_uint(x);
    return (u + 0x7fffu + ((u >> 16) & 1u)) >> 16;
}

// ================= fused front: bucket histogram (blocks 0..NWG) + x moments =================
__global__ __launch_bounds__(256) void k_front(const int* __restrict__ ei,
    int* __restrict__ counts, const float* __restrict__ x, float* __restrict__ mom)
{
    int t = threadIdx.x;
    if (blockIdx.x < NWG) {
        __shared__ int hist[NB];
        int wg = blockIdx.x;
        if (t < NB) hist[t] = 0;
        __syncthreads();
        int base = wg * CHUNK;
        for (int i = t; i < CHUNK; i += 256)
            atomicAdd(&hist[ei[NE + base + i] >> 9], 1);
        __syncthreads();
        if (t < NB) counts[wg * NB + t] = hist[t];      // [w][bucket], coalesced
    } else {
        int mb = blockIdx.x - NWG;
        float s0=0,s1=0,s2=0,m00=0,m01=0,m02=0,m11=0,m12=0,m22=0;
        for (int n = mb * 256 + t; n < NN; n += MOMB * 256) {
            float a = x[n*3], b = x[n*3+1], c = x[n*3+2];
            s0 += a; s1 += b; s2 += c;
            m00 = fmaf(a,a,m00); m01 = fmaf(a,b,m01); m02 = fmaf(a,c,m02);
            m11 = fmaf(b,b,m11); m12 = fmaf(b,c,m12); m22 = fmaf(c,c,m22);
        }
        #pragma unroll
        for (int off = 32; off; off >>= 1) {
            s0 += __shfl_xor(s0, off); s1 += __shfl_xor(s1, off); s2 += __shfl_xor(s2, off);
            m00 += __shfl_xor(m00, off); m01 += __shfl_xor(m01, off); m02 += __shfl_xor(m02, off);
            m11 += __shfl_xor(m11, off); m12 += __shfl_xor(m12, off); m22 += __shfl_xor(m22, off);
        }
        __shared__ float red[4][9];
        int wave = t >> 6, lane = t & 63;
        if (lane == 0) {
            red[wave][0]=s0; red[wave][1]=s1; red[wave][2]=s2;
            red[wave][3]=m00; red[wave][4]=m01; red[wave][5]=m02;
            red[wave][6]=m11; red[wave][7]=m12; red[wave][8]=m22;
        }
        __syncthreads();
        if (t < 9) {
            float v = red[0][t] + red[1][t] + red[2][t] + red[3][t];
            atomicAdd(&mom[t], v);
        }
    }
}

// analytic BN scale for channel k from x-moments
__device__ __forceinline__ float bn_scale_of(const float* __restrict__ mom,
    const float* __restrict__ fnw, const float* __restrict__ fnb,
    const float* __restrict__ gamma, int k)
{
    float w0 = fnw[k], w1 = fnw[64 + k], w2 = fnw[128 + k], bc = fnb[k];
    float dot  = mom[0]*w0 + mom[1]*w1 + mom[2]*w2;
    float quad = mom[3]*w0*w0 + 2.f*mom[4]*w0*w1 + 2.f*mom[5]*w0*w2
               + mom[6]*w1*w1 + 2.f*mom[7]*w1*w2 + mom[8]*w2*w2;
    float mean = dot * (1.0f / NN) + bc;
    float eh2  = quad * (1.0f / NN) + 2.f * bc * dot * (1.0f / NN) + bc * bc;
    float var  = eh2 - mean * mean;
    return gamma[k] * rsqrtf(var + BN_EPS);
}

// ================= fused mid: params (block 0) + bscan (block 1) + prep (blocks 2+) =================
// Attention-path quantities (u, c0, Mi, Mj) pre-scaled by LOG2E -> edge kernel uses exp2.
__global__ __launch_bounds__(256) void k_mid(const float* __restrict__ mom,
    const float* __restrict__ fnw, const float* __restrict__ fnb,
    const float* __restrict__ gamma, const float* __restrict__ beta,
    const float* __restrict__ few, const float* __restrict__ feb,
    const float* __restrict__ attn_w, const float* __restrict__ attn_b,
    const float* __restrict__ fcb, const float* __restrict__ fcw,
    int* __restrict__ counts, int* __restrict__ bbase, int* __restrict__ row_ptr,
    float* __restrict__ u, float* __restrict__ c0, float* __restrict__ feff,
    unsigned short* __restrict__ wt)
{
    int t = threadIdx.x;
    if (blockIdx.x == 0) {
        // ---- params ----
        __shared__ float ssh[64], sfe[3][64];
        if (t < 64) {
            float w0 = fnw[t], w1 = fnw[64 + t], w2 = fnw[128 + t], bc = fnb[t];
            float dot  = mom[0]*w0 + mom[1]*w1 + mom[2]*w2;
            float quad = mom[3]*w0*w0 + 2.f*mom[4]*w0*w1 + 2.f*mom[5]*w0*w2
                       + mom[6]*w1*w1 + 2.f*mom[7]*w1*w2 + mom[8]*w2*w2;
            float mean = dot * (1.0f / NN) + bc;
            float eh2  = quad * (1.0f / NN) + 2.f * bc * dot * (1.0f / NN) + bc * bc;
            float var  = eh2 - mean * mean;
            float sc   = gamma[t] * rsqrtf(var + BN_EPS);
            ssh[t] = beta[t] - mean * sc;
        }
        __syncthreads();
        if (t < 64) {
            float v = 0.f;                              // v = sh @ W0_0
            for (int k = 0; k < 64; k++) v = fmaf(ssh[k], fcw[k * 64 + t], v);
            sfe[0][t] = fcb[t] + v;
            sfe[1][t] = fcb[64 + t];
            sfe[2][t] = fcb[128 + t];
        }
        __syncthreads();
        if (t < 192) {
            int l = t >> 6, c = t & 63;
            const float* AW = attn_w + l * 144 * 64;
            float uu = 0.f, cc = 0.f;
            for (int j = 0; j < 16; j++) {
                float wv = AW[(128 + j) * 64 + c];
                uu = fmaf(few[j], wv, uu);
                cc = fmaf(feb[j], wv, cc);
            }
            float bi = 0.f;                             // fcb_eff @ (Wi + Wj)
            for (int tt = 0; tt < 64; tt++)
                bi = fmaf(sfe[l][tt], AW[tt * 64 + c] + AW[(64 + tt) * 64 + c], bi);
            u[t]    = uu * LOG2E;
            c0[t]   = (cc + attn_b[t] + bi) * LOG2E;
            feff[t] = sfe[l][c];
        }
    } else if (blockIdx.x == 1) {
        // ---- bscan ----
        __shared__ int s_tot[256];
        int tot = 0;
        if (t < NB)
            for (int w = 0; w < NWG; w++) tot += counts[w * NB + t];
        s_tot[t] = tot;
        __syncthreads();
        for (int off = 1; off < 256; off <<= 1) {
            int v = (t >= off) ? s_tot[t - off] : 0;
            __syncthreads();
            s_tot[t] += v;
            __syncthreads();
        }
        int excl = s_tot[t] - tot;
        if (t < NB) {
            bbase[t] = excl;
            int run = excl;
            for (int w = 0; w < NWG; w++) {
                int c = counts[w * NB + t];
                counts[w * NB + t] = run;
                run += c;
            }
            if (t == NB - 1) {
                bbase[NB] = run;          // == NE
                row_ptr[NN] = run;
            }
        }
    } else {
        // ---- prep: 4 tasks of 64 threads per block ----
        int task = (blockIdx.x - 2) * 4 + (t >> 6);
        int k = t & 63;
        int l = task / 192, g = task - l * 192;
        const float* W0 = fcw + l * 4096;
        float scale = (l == 0) ? bn_scale_of(mom, fnw, fnb, gamma, k) : 1.0f;
        float v;
        if (g < 64) {
            v = W0[k * 64 + g] * scale;
        } else {
            int c = g & 63;
            const float* Wx = attn_w + l * 144 * 64 + (g < 128 ? 0 : 4096);
            float s = 0.f;
            for (int tt = 0; tt < 64; tt++) s = fmaf(W0[k * 64 + tt], Wx[tt * 64 + c], s);
            v = s * scale * LOG2E;                      // attention path: fold log2(e)
        }
        wt[(l * 192 + g) * 64 + k] = (unsigned short)f2bf(v);
    }
}

// ================= tf core (per-quadrant, low-VGPR): [hl | ai | aj] = A @ [W0 | Mi | Mj] =================
__device__ __forceinline__ void tf_core(const bf16x8* a, const unsigned short* __restrict__ wt_l,
    const float* __restrict__ feff_l, const float* __restrict__ c0_l,
    float* __restrict__ ai, unsigned* __restrict__ packed, int n0, int r16, int quad)
{
    const unsigned short* wb = wt_l + (size_t)r16 * 64 + quad * 8;
    #pragma unroll
    for (int cq = 0; cq < 4; cq++) {
        f32x4 ah = {0.f,0.f,0.f,0.f}, aa = {0.f,0.f,0.f,0.f}, aj = {0.f,0.f,0.f,0.f};
        ah = __builtin_amdgcn_mfma_f32_16x16x32_bf16(a[0], *(const bf16x8*)(wb + cq * 1024), ah, 0, 0, 0);
        ah = __builtin_amdgcn_mfma_f32_16x16x32_bf16(a[1], *(const bf16x8*)(wb + cq * 1024 + 32), ah, 0, 0, 0);
        aa = __builtin_amdgcn_mfma_f32_16x16x32_bf16(a[0], *(const bf16x8*)(wb + (4 + cq) * 1024), aa, 0, 0, 0);
        aa = __builtin_amdgcn_mfma_f32_16x16x32_bf16(a[1], *(const bf16x8*)(wb + (4 + cq) * 1024 + 32), aa, 0, 0, 0);
        aj = __builtin_amdgcn_mfma_f32_16x16x32_bf16(a[0], *(const bf16x8*)(wb + (8 + cq) * 1024), aj, 0, 0, 0);
        aj = __builtin_amdgcn_mfma_f32_16x16x32_bf16(a[1], *(const bf16x8*)(wb + (8 + cq) * 1024 + 32), aj, 0, 0, 0);
        float fe = feff_l[cq * 16 + r16], cc = c0_l[cq * 16 + r16];
        #pragma unroll
        for (int r = 0; r < 4; r++) {
            int nd = n0 + quad * 4 + r;
            if (nd < NN) {
                size_t base = (size_t)nd * 64 + cq * 16 + r16;
                ai[base]     = aa[r] + cc;                       // c0 folded in
                packed[base] = f2bf(ah[r] + fe) | (f2bf(aj[r]) << 16);
            }
        }
    }
}

// ================= fused l3: bwrite (blocks 0..NWG) + tf layer 0 =================
__global__ __launch_bounds__(256) void k_l3(const int* __restrict__ ei,
    const float* __restrict__ ea, const int* __restrict__ counts, int2* __restrict__ brec,
    const float* __restrict__ xin, const float* __restrict__ fnw, const float* __restrict__ fnb,
    const unsigned short* __restrict__ wt, const float* __restrict__ feff,
    const float* __restrict__ c0v, float* __restrict__ ai, unsigned* __restrict__ packed)
{
    int t = threadIdx.x;
    if (blockIdx.x < NWG) {
        __shared__ int off[NB];
        int wg = blockIdx.x;
        if (t < NB) off[t] = counts[wg * NB + t];
        __syncthreads();
        int base = wg * CHUNK;
        for (int i = t; i < CHUNK; i += 256) {
            int k = base + i;
            int s = ei[k], d = ei[NE + k];
            int b = d >> 9;
            int j = atomicAdd(&off[b], 1);
            brec[j] = make_int2(((d & 511) << 17) | s, __float_as_int(ea[k]));
        }
    } else {
        int bid = blockIdx.x - NWG;
        int wv = t >> 6, l = t & 63;
        int r16 = l & 15, quad = l >> 4;
        int n0 = bid * 64 + wv * 16;
        int na = n0 + r16; if (na >= NN) na = NN - 1;
        float x0 = xin[na*3], x1 = xin[na*3+1], x2 = xin[na*3+2];
        bf16x8 a[2];
        #pragma unroll
        for (int ks = 0; ks < 2; ks++) {
            bf16x8 tt;
            #pragma unroll
            for (int e = 0; e < 8; e++) {
                int c = quad * 8 + ks * 32 + e;
                float v = fmaf(x0, fnw[c], fmaf(x1, fnw[64 + c], fmaf(x2, fnw[128 + c], fnb[c])));
                tt[e] = (short)f2bf(v);
            }
            a[ks] = tt;
        }
        tf_core(a, wt, feff, c0v, ai, packed, n0, r16, quad);
    }
}

// ================= csr finalize (one WG per bucket) =================
__global__ __launch_bounds__(256) void k_csr(const int2* __restrict__ brec,
    const int* __restrict__ bbase, int* __restrict__ row_ptr, int2* __restrict__ er)
{
    __shared__ int s_cnt[512], s_excl[512], s_ts[256];
    int t = threadIdx.x, b = blockIdx.x;
    int beg = bbase[b], end = bbase[b + 1];
    s_cnt[t] = 0; s_cnt[t + 256] = 0;
    __syncthreads();
    for (int i = beg + t; i < end; i += 256)
        atomicAdd(&s_cnt[brec[i].x >> 17], 1);
    __syncthreads();
    int a0 = s_cnt[2 * t], a1 = s_cnt[2 * t + 1];
    int ts = a0 + a1;
    s_ts[t] = ts;
    __syncthreads();
    for (int off = 1; off < 256; off <<= 1) {
        int v = (t >= off) ? s_ts[t - off] : 0;
        __syncthreads();
        s_ts[t] += v;
        __syncthreads();
    }
    int et = s_ts[t] - ts;
    s_excl[2 * t] = et; s_excl[2 * t + 1] = et + a0;
    s_cnt[t] = 0; s_cnt[t + 256] = 0;
    __syncthreads();
    #pragma unroll
    for (int q = 0; q < 2; q++) {
        int dl = t + q * 256;
        int n = b * 512 + dl;
        if (n < NN) row_ptr[n] = beg + s_excl[dl];
    }
    for (int i = beg + t; i < end; i += 256) {
        int2 r = brec[i];
        int dl = r.x >> 17;
        int pos = atomicAdd(&s_cnt[dl], 1);
        er[beg + s_excl[dl] + pos] = make_int2(r.x & 0x1FFFF, r.y);
    }
}

// ================= fused edge aggregate (1 node/wave) + next-layer transform =================
// 1024-thread blocks: 16 waves, each aggregates ONE node (max wave parallelism,
// identical per-wave loop to the proven k_edge). Then waves 0-3 MFMA-transform
// the block's 16-row tile from LDS (one column-quadrant per wave, low VGPR).
#define EDGE_STEP(q, dacc, sacc) { \
    float aa = fmaf(__int_as_float(e[q].y), uc, base + __uint_as_float(p[q] & 0xffff0000u)); \
    aa = fmaxf(aa, NEG * aa); \
    float xx = EXP2(aa); \
    dacc += xx; sacc = fmaf(xx, __uint_as_float(p[q] << 16), sacc); }

template<int DOTF>
__global__ __launch_bounds__(1024) void k_edgetf(const unsigned* __restrict__ packed_r,
    float* __restrict__ ai, const int* __restrict__ row_ptr,
    const int2* __restrict__ er, const float* __restrict__ u_l,
    const unsigned short* __restrict__ wt_n, const float* __restrict__ feff_n,
    const float* __restrict__ c0_n, unsigned* __restrict__ packed_w,
    float* __restrict__ outp)
{
    __shared__ float hlds[16][68];
    int t = threadIdx.x;
    int wv = t >> 6, lane = t & 63;
    int n = blockIdx.x * 16 + wv;                 // grid exact NN/16
    int beg = row_ptr[n], end = row_ptr[n + 1];
    float base = ai[(size_t)n * 64 + lane];       // c0 folded in (log2 domain)
    float uc = u_l[lane];
    const unsigned* __restrict__ pc = packed_r + lane;
    float d0 = 0.f, d1 = 0.f, s0 = 0.f, s1 = 0.f;
    int k = beg;
    for (; k + 16 <= end; k += 16) {
        int2 e[16]; unsigned p[16];
        #pragma unroll
        for (int q = 0; q < 16; q++) e[q] = er[k + q];
        #pragma unroll
        for (int q = 0; q < 16; q++) p[q] = pc[(size_t)e[q].x << 6];
        #pragma unroll
        for (int q = 0; q < 16; q++) {
            if (q & 1) EDGE_STEP(q, d1, s1) else EDGE_STEP(q, d0, s0)
        }
    }
    for (; k + 8 <= end; k += 8) {
        int2 e[8]; unsigned p[8];
        #pragma unroll
        for (int q = 0; q < 8; q++) e[q] = er[k + q];
        #pragma unroll
        for (int q = 0; q < 8; q++) p[q] = pc[(size_t)e[q].x << 6];
        #pragma unroll
        for (int q = 0; q < 8; q++) {
            if (q & 1) EDGE_STEP(q, d1, s1) else EDGE_STEP(q, d0, s0)
        }
    }
    for (; k + 4 <= end; k += 4) {
        int2 e[4]; unsigned p[4];
        #pragma unroll
        for (int q = 0; q < 4; q++) e[q] = er[k + q];
        #pragma unroll
        for (int q = 0; q < 4; q++) p[q] = pc[(size_t)e[q].x << 6];
        #pragma unroll
        for (int q = 0; q < 4; q++) {
            if (q & 1) EDGE_STEP(q, d1, s1) else EDGE_STEP(q, d0, s0)
        }
    }
    for (; k < end; k++) {
        int2 e[1]; unsigned p[1];
        e[0] = er[k];
        p[0] = pc[(size_t)e[0].x << 6];
        EDGE_STEP(0, d0, s0)
    }
    float hv = (s0 + s1) / (d0 + d1 + 1e-16f);
    if (DOTF) {
        hlds[wv][lane] = hv;
        __syncthreads();
        if (wv < 4) {
            int r16 = lane & 15, quad = lane >> 4;
            const float* hp = &hlds[r16][quad * 8];
            bf16x8 a[2];
            #pragma unroll
            for (int ks = 0; ks < 2; ks++) {
                f32x4 lo = *(const f32x4*)(hp + ks * 32);
                f32x4 hi = *(const f32x4*)(hp + ks * 32 + 4);
                bf16x8 tt;
                tt[0] = (short)f2bf(lo[0]); tt[1] = (short)f2bf(lo[1]);
                tt[2] = (short)f2bf(lo[2]); tt[3] = (short)f2bf(lo[3]);
                tt[4] = (short)f2bf(hi[0]); tt[5] = (short)f2bf(hi[1]);
                tt[6] = (short)f2bf(hi[2]); tt[7] = (short)f2bf(hi[3]);
                a[ks] = tt;
            }
            const unsigned short* wb = wt_n + (size_t)r16 * 64 + quad * 8;
            int cq = wv;                           // one column-quadrant per wave
            f32x4 ah = {0.f,0.f,0.f,0.f}, aa = {0.f,0.f,0.f,0.f}, aj = {0.f,0.f,0.f,0.f};
            ah = __builtin_amdgcn_mfma_f32_16x16x32_bf16(a[0], *(const bf16x8*)(wb + cq * 1024), ah, 0, 0, 0);
            ah = __builtin_amdgcn_mfma_f32_16x16x32_bf16(a[1], *(const bf16x8*)(wb + cq * 1024 + 32), ah, 0, 0, 0);
            aa = __builtin_amdgcn_mfma_f32_16x16x32_bf16(a[0], *(const bf16x8*)(wb + (4 + cq) * 1024), aa, 0, 0, 0);
            aa = __builtin_amdgcn_mfma_f32_16x16x32_bf16(a[1], *(const bf16x8*)(wb + (4 + cq) * 1024 + 32), aa, 0, 0, 0);
            aj = __builtin_amdgcn_mfma_f32_16x16x32_bf16(a[0], *(const bf16x8*)(wb + (8 + cq) * 1024), aj, 0, 0, 0);
            aj = __builtin_amdgcn_mfma_f32_16x16x32_bf16(a[1], *(const bf16x8*)(wb + (8 + cq) * 1024 + 32), aj, 0, 0, 0);
            float fe = feff_n[cq * 16 + r16], cc = c0_n[cq * 16 + r16];
            #pragma unroll
            for (int r = 0; r < 4; r++) {
                int nd = blockIdx.x * 16 + quad * 4 + r;
                size_t ob = (size_t)nd * 64 + cq * 16 + r16;
                ai[ob]       = aa[r] + cc;
                packed_w[ob] = f2bf(ah[r] + fe) | (f2bf(aj[r]) << 16);
            }
        }
    } else {
        outp[(size_t)n * 64 + lane] = hv;
    }
}

// ---------------- launch ----------------
extern "C" void kernel_launch(void* const* d_in, const int* in_sizes, int n_in,
                              void* d_out, int out_size, void* d_ws, size_t ws_size,
                              hipStream_t stream)
{
    const float* x    = (const float*)d_in[0];
    const float* ea   = (const float*)d_in[1];
    const int*   ei   = (const int*)d_in[2];
    const float* fnw  = (const float*)d_in[3];
    const float* fnb  = (const float*)d_in[4];
    const float* few  = (const float*)d_in[5];
    const float* feb  = (const float*)d_in[6];
    const float* gmm  = (const float*)d_in[7];
    const float* beta = (const float*)d_in[8];
    const float* fcw  = (const float*)d_in[9];
    const float* fcb  = (const float*)d_in[10];
    const float* aw   = (const float*)d_in[11];
    const float* ab   = (const float*)d_in[12];
    float* out = (float*)d_out;

    char* ws = (char*)d_ws;
    size_t off = 0;
    auto alloc = [&](size_t bytes) -> void* {
        void* p = ws + off;
        off += (bytes + 255) / 256 * 256;
        return p;
    };
    float*    ai      = (float*)   alloc((size_t)NN * 64 * 4);
    unsigned* packed0 = (unsigned*)alloc((size_t)NN * 64 * 4);
    unsigned* packed1 = (unsigned*)alloc((size_t)NN * 64 * 4);
    int2*     er      = (int2*)    alloc((size_t)NE * 8);
    int2*     brec    = (int2*)    alloc((size_t)NE * 8);
    int*      row_ptr = (int*)     alloc((size_t)(NN + 1) * 4);
    int*      counts  = (int*)     alloc((size_t)NB * NWG * 4);
    int*      bbase   = (int*)     alloc((NB + 1) * 4);
    float*    mom     = (float*)   alloc(12 * 4);
    float*    uvec    = (float*)   alloc(192 * 4);
    float*    c0vec   = (float*)   alloc(192 * 4);
    float*    feff    = (float*)   alloc(192 * 4);
    unsigned short* wt = (unsigned short*)alloc((size_t)LAYERS * 192 * 64 * 2);

    (void)hipMemsetAsync(mom, 0, 12 * 4, stream);

    // L1: bucket histogram + x moments
    k_front<<<NWG + MOMB, 256, 0, stream>>>(ei, counts, x, mom);
    // L2: params + bucket scan + weight prep (attention path pre-scaled by log2e)
    k_mid<<<2 + 144, 256, 0, stream>>>(mom, fnw, fnb, gmm, beta, few, feb, aw, ab,
                                       fcb, fcw, counts, bbase, row_ptr,
                                       uvec, c0vec, feff, wt);
    // L3: bucket write + tf layer 0 -> ai, packed0
    k_l3<<<NWG + TFB, 256, 0, stream>>>(ei, ea, counts, brec, x, fnw, fnb,
                                        wt, feff, c0vec, ai, packed0);
    // L4: csr finalize
    k_csr<<<NB, 256, 0, stream>>>(brec, bbase, row_ptr, er);
    // L5: edge layer0 + tf layer1 -> ai (in place), packed1
    k_edgetf<1><<<ETB, 1024, 0, stream>>>(packed0, ai, row_ptr, er, uvec,
                                          wt + (size_t)192 * 64, feff + 64, c0vec + 64,
                                          packed1, out);
    // L6: edge layer1 + tf layer2 -> ai (in place), packed0
    k_edgetf<1><<<ETB, 1024, 0, stream>>>(packed1, ai, row_ptr, er, uvec + 64,
                                          wt + (size_t)2 * 192 * 64, feff + 128, c0vec + 128,
                                          packed0, out);
    // L7: edge layer2 -> out
    k_edgetf<0><<<ETB, 1024, 0, stream>>>(packed0, ai, row_ptr, er, uvec + 128,
                                          wt, feff, c0vec, packed1, out);
    (void)in_sizes; (void)n_in; (void)out_size; (void)ws_size;
}

// Round 15
// 437.100 us; speedup vs baseline: 1.1684x; 1.1684x over previous
//
#include <hip/hip_runtime.h>
#include <math.h>

#define NN 100000
#define NE 1600000
#define LAYERS 3
#define NEG 0.2f
#define BN_EPS 1e-5f
#define LOG2E 1.4426950408889634f

#define NB 196            // buckets = ceil(NN / 512)
#define NWG 512           // multisplit workgroups
#define CHUNK 3125        // NE / NWG exactly
#define MOMB 304          // moments blocks
#define TFB 1563          // tf blocks = ceil(NN/64)

typedef __attribute__((ext_vector_type(8))) short bf16x8;
typedef __attribute__((ext_vector_type(4))) float f32x4;

#if __has_builtin(__builtin_amdgcn_exp2f)
#define EXP2(x) __builtin_amdgcn_exp2f(x)
#else
#define EXP2(x) __expf((x) * 0.6931471805599453f)
#endif

__device__ __forceinline__ unsigned f2bf(float x) {   // fp32 -> bf16 bits, RNE
    unsigned u = __float_as_uint(x);
    return (u + 0x7fffu + ((u >> 16) & 1u)) >> 16;
}

// ================= fused front: bucket histogram (blocks 0..NWG) + x moments =================
__global__ __launch_bounds__(256) void k_front(const int* __restrict__ ei,
    int* __restrict__ counts, const float* __restrict__ x, float* __restrict__ mom)
{
    int t = threadIdx.x;
    if (blockIdx.x < NWG) {
        __shared__ int hist[NB];
        int wg = blockIdx.x;
        if (t < NB) hist[t] = 0;
        __syncthreads();
        int base = wg * CHUNK;
        for (int i = t; i < CHUNK; i += 256)
            atomicAdd(&hist[ei[NE + base + i] >> 9], 1);
        __syncthreads();
        if (t < NB) counts[wg * NB + t] = hist[t];      // [w][bucket], coalesced
    } else {
        int mb = blockIdx.x - NWG;
        float s0=0,s1=0,s2=0,m00=0,m01=0,m02=0,m11=0,m12=0,m22=0;
        for (int n = mb * 256 + t; n < NN; n += MOMB * 256) {
            float a = x[n*3], b = x[n*3+1], c = x[n*3+2];
            s0 += a; s1 += b; s2 += c;
            m00 = fmaf(a,a,m00); m01 = fmaf(a,b,m01); m02 = fmaf(a,c,m02);
            m11 = fmaf(b,b,m11); m12 = fmaf(b,c,m12); m22 = fmaf(c,c,m22);
        }
        #pragma unroll
        for (int off = 32; off; off >>= 1) {
            s0 += __shfl_xor(s0, off); s1 += __shfl_xor(s1, off); s2 += __shfl_xor(s2, off);
            m00 += __shfl_xor(m00, off); m01 += __shfl_xor(m01, off); m02 += __shfl_xor(m02, off);
            m11 += __shfl_xor(m11, off); m12 += __shfl_xor(m12, off); m22 += __shfl_xor(m22, off);
        }
        __shared__ float red[4][9];
        int wave = t >> 6, lane = t & 63;
        if (lane == 0) {
            red[wave][0]=s0; red[wave][1]=s1; red[wave][2]=s2;
            red[wave][3]=m00; red[wave][4]=m01; red[wave][5]=m02;
            red[wave][6]=m11; red[wave][7]=m12; red[wave][8]=m22;
        }
        __syncthreads();
        if (t < 9) {
            float v = red[0][t] + red[1][t] + red[2][t] + red[3][t];
            atomicAdd(&mom[t], v);
        }
    }
}

// analytic BN scale for channel k from x-moments
__device__ __forceinline__ float bn_scale_of(const float* __restrict__ mom,
    const float* __restrict__ fnw, const float* __restrict__ fnb,
    const float* __restrict__ gamma, int k)
{
    float w0 = fnw[k], w1 = fnw[64 + k], w2 = fnw[128 + k], bc = fnb[k];
    float dot  = mom[0]*w0 + mom[1]*w1 + mom[2]*w2;
    float quad = mom[3]*w0*w0 + 2.f*mom[4]*w0*w1 + 2.f*mom[5]*w0*w2
               + mom[6]*w1*w1 + 2.f*mom[7]*w1*w2 + mom[8]*w2*w2;
    float mean = dot * (1.0f / NN) + bc;
    float eh2  = quad * (1.0f / NN) + 2.f * bc * dot * (1.0f / NN) + bc * bc;
    float var  = eh2 - mean * mean;
    return gamma[k] * rsqrtf(var + BN_EPS);
}

// ================= fused mid: params (block 0) + bscan (block 1) + prep (blocks 2+) =================
// Attention-path quantities (u, c0, Mi, Mj) pre-scaled by LOG2E -> edge kernel uses exp2.
__global__ __launch_bounds__(256) void k_mid(const float* __restrict__ mom,
    const float* __restrict__ fnw, const float* __restrict__ fnb,
    const float* __restrict__ gamma, const float* __restrict__ beta,
    const float* __restrict__ few, const float* __restrict__ feb,
    const float* __restrict__ attn_w, const float* __restrict__ attn_b,
    const float* __restrict__ fcb, const float* __restrict__ fcw,
    int* __restrict__ counts, int* __restrict__ bbase, int* __restrict__ row_ptr,
    float* __restrict__ u, float* __restrict__ c0, float* __restrict__ feff,
    unsigned short* __restrict__ wt)
{
    int t = threadIdx.x;
    if (blockIdx.x == 0) {
        // ---- params ----
        __shared__ float ssh[64], sfe[3][64];
        if (t < 64) {
            float w0 = fnw[t], w1 = fnw[64 + t], w2 = fnw[128 + t], bc = fnb[t];
            float dot  = mom[0]*w0 + mom[1]*w1 + mom[2]*w2;
            float quad = mom[3]*w0*w0 + 2.f*mom[4]*w0*w1 + 2.f*mom[5]*w0*w2
                       + mom[6]*w1*w1 + 2.f*mom[7]*w1*w2 + mom[8]*w2*w2;
            float mean = dot * (1.0f / NN) + bc;
            float eh2  = quad * (1.0f / NN) + 2.f * bc * dot * (1.0f / NN) + bc * bc;
            float var  = eh2 - mean * mean;
            float sc   = gamma[t] * rsqrtf(var + BN_EPS);
            ssh[t] = beta[t] - mean * sc;
        }
        __syncthreads();
        if (t < 64) {
            float v = 0.f;                              // v = sh @ W0_0
            for (int k = 0; k < 64; k++) v = fmaf(ssh[k], fcw[k * 64 + t], v);
            sfe[0][t] = fcb[t] + v;
            sfe[1][t] = fcb[64 + t];
            sfe[2][t] = fcb[128 + t];
        }
        __syncthreads();
        if (t < 192) {
            int l = t >> 6, c = t & 63;
            const float* AW = attn_w + l * 144 * 64;
            float uu = 0.f, cc = 0.f;
            for (int j = 0; j < 16; j++) {
                float wv = AW[(128 + j) * 64 + c];
                uu = fmaf(few[j], wv, uu);
                cc = fmaf(feb[j], wv, cc);
            }
            float bi = 0.f;                             // fcb_eff @ (Wi + Wj)
            for (int tt = 0; tt < 64; tt++)
                bi = fmaf(sfe[l][tt], AW[tt * 64 + c] + AW[(64 + tt) * 64 + c], bi);
            u[t]    = uu * LOG2E;
            c0[t]   = (cc + attn_b[t] + bi) * LOG2E;
            feff[t] = sfe[l][c];
        }
    } else if (blockIdx.x == 1) {
        // ---- bscan ----
        __shared__ int s_tot[256];
        int tot = 0;
        if (t < NB)
            for (int w = 0; w < NWG; w++) tot += counts[w * NB + t];
        s_tot[t] = tot;
        __syncthreads();
        for (int off = 1; off < 256; off <<= 1) {
            int v = (t >= off) ? s_tot[t - off] : 0;
            __syncthreads();
            s_tot[t] += v;
            __syncthreads();
        }
        int excl = s_tot[t] - tot;
        if (t < NB) {
            bbase[t] = excl;
            int run = excl;
            for (int w = 0; w < NWG; w++) {
                int c = counts[w * NB + t];
                counts[w * NB + t] = run;
                run += c;
            }
            if (t == NB - 1) {
                bbase[NB] = run;          // == NE
                row_ptr[NN] = run;
            }
        }
    } else {
        // ---- prep: 4 tasks of 64 threads per block ----
        int task = (blockIdx.x - 2) * 4 + (t >> 6);
        int k = t & 63;
        int l = task / 192, g = task - l * 192;
        const float* W0 = fcw + l * 4096;
        float scale = (l == 0) ? bn_scale_of(mom, fnw, fnb, gamma, k) : 1.0f;
        float v;
        if (g < 64) {
            v = W0[k * 64 + g] * scale;
        } else {
            int c = g & 63;
            const float* Wx = attn_w + l * 144 * 64 + (g < 128 ? 0 : 4096);
            float s = 0.f;
            for (int tt = 0; tt < 64; tt++) s = fmaf(W0[k * 64 + tt], Wx[tt * 64 + c], s);
            v = s * scale * LOG2E;                      // attention path: fold log2(e)
        }
        wt[(l * 192 + g) * 64 + k] = (unsigned short)f2bf(v);
    }
}

// ================= tf core (per-quadrant, low-VGPR): [hl | ai | aj] = A @ [W0 | Mi | Mj] =================
__device__ __forceinline__ void tf_core(const bf16x8* a, const unsigned short* __restrict__ wt_l,
    const float* __restrict__ feff_l, const float* __restrict__ c0_l,
    float* __restrict__ ai, unsigned* __restrict__ packed, int n0, int r16, int quad)
{
    const unsigned short* wb = wt_l + (size_t)r16 * 64 + quad * 8;
    #pragma unroll
    for (int cq = 0; cq < 4; cq++) {
        f32x4 ah = {0.f,0.f,0.f,0.f}, aa = {0.f,0.f,0.f,0.f}, aj = {0.f,0.f,0.f,0.f};
        ah = __builtin_amdgcn_mfma_f32_16x16x32_bf16(a[0], *(const bf16x8*)(wb + cq * 1024), ah, 0, 0, 0);
        ah = __builtin_amdgcn_mfma_f32_16x16x32_bf16(a[1], *(const bf16x8*)(wb + cq * 1024 + 32), ah, 0, 0, 0);
        aa = __builtin_amdgcn_mfma_f32_16x16x32_bf16(a[0], *(const bf16x8*)(wb + (4 + cq) * 1024), aa, 0, 0, 0);
        aa = __builtin_amdgcn_mfma_f32_16x16x32_bf16(a[1], *(const bf16x8*)(wb + (4 + cq) * 1024 + 32), aa, 0, 0, 0);
        aj = __builtin_amdgcn_mfma_f32_16x16x32_bf16(a[0], *(const bf16x8*)(wb + (8 + cq) * 1024), aj, 0, 0, 0);
        aj = __builtin_amdgcn_mfma_f32_16x16x32_bf16(a[1], *(const bf16x8*)(wb + (8 + cq) * 1024 + 32), aj, 0, 0, 0);
        float fe = feff_l[cq * 16 + r16], cc = c0_l[cq * 16 + r16];
        #pragma unroll
        for (int r = 0; r < 4; r++) {
            int nd = n0 + quad * 4 + r;
            if (nd < NN) {
                size_t base = (size_t)nd * 64 + cq * 16 + r16;
                ai[base]     = aa[r] + cc;                       // c0 folded in
                packed[base] = f2bf(ah[r] + fe) | (f2bf(aj[r]) << 16);
            }
        }
    }
}

// ================= fused l3: bwrite (blocks 0..NWG) + tf layer 0 =================
__global__ __launch_bounds__(256) void k_l3(const int* __restrict__ ei,
    const float* __restrict__ ea, const int* __restrict__ counts, int2* __restrict__ brec,
    const float* __restrict__ xin, const float* __restrict__ fnw, const float* __restrict__ fnb,
    const unsigned short* __restrict__ wt, const float* __restrict__ feff,
    const float* __restrict__ c0v, float* __restrict__ ai, unsigned* __restrict__ packed)
{
    int t = threadIdx.x;
    if (blockIdx.x < NWG) {
        __shared__ int off[NB];
        int wg = blockIdx.x;
        if (t < NB) off[t] = counts[wg * NB + t];
        __syncthreads();
        int base = wg * CHUNK;
        for (int i = t; i < CHUNK; i += 256) {
            int k = base + i;
            int s = ei[k], d = ei[NE + k];
            int b = d >> 9;
            int j = atomicAdd(&off[b], 1);
            brec[j] = make_int2(((d & 511) << 17) | s, __float_as_int(ea[k]));
        }
    } else {
        int bid = blockIdx.x - NWG;
        int wv = t >> 6, l = t & 63;
        int r16 = l & 15, quad = l >> 4;
        int n0 = bid * 64 + wv * 16;
        int na = n0 + r16; if (na >= NN) na = NN - 1;
        float x0 = xin[na*3], x1 = xin[na*3+1], x2 = xin[na*3+2];
        bf16x8 a[2];
        #pragma unroll
        for (int ks = 0; ks < 2; ks++) {
            bf16x8 tt;
            #pragma unroll
            for (int e = 0; e < 8; e++) {
                int c = quad * 8 + ks * 32 + e;
                float v = fmaf(x0, fnw[c], fmaf(x1, fnw[64 + c], fmaf(x2, fnw[128 + c], fnb[c])));
                tt[e] = (short)f2bf(v);
            }
            a[ks] = tt;
        }
        tf_core(a, wt, feff, c0v, ai, packed, n0, r16, quad);
    }
}

// ================= csr finalize (one WG per bucket) =================
__global__ __launch_bounds__(256) void k_csr(const int2* __restrict__ brec,
    const int* __restrict__ bbase, int* __restrict__ row_ptr, int2* __restrict__ er)
{
    __shared__ int s_cnt[512], s_excl[512], s_ts[256];
    int t = threadIdx.x, b = blockIdx.x;
    int beg = bbase[b], end = bbase[b + 1];
    s_cnt[t] = 0; s_cnt[t + 256] = 0;
    __syncthreads();
    for (int i = beg + t; i < end; i += 256)
        atomicAdd(&s_cnt[brec[i].x >> 17], 1);
    __syncthreads();
    int a0 = s_cnt[2 * t], a1 = s_cnt[2 * t + 1];
    int ts = a0 + a1;
    s_ts[t] = ts;
    __syncthreads();
    for (int off = 1; off < 256; off <<= 1) {
        int v = (t >= off) ? s_ts[t - off] : 0;
        __syncthreads();
        s_ts[t] += v;
        __syncthreads();
    }
    int et = s_ts[t] - ts;
    s_excl[2 * t] = et; s_excl[2 * t + 1] = et + a0;
    s_cnt[t] = 0; s_cnt[t + 256] = 0;
    __syncthreads();
    #pragma unroll
    for (int q = 0; q < 2; q++) {
        int dl = t + q * 256;
        int n = b * 512 + dl;
        if (n < NN) row_ptr[n] = beg + s_excl[dl];
    }
    for (int i = beg + t; i < end; i += 256) {
        int2 r = brec[i];
        int dl = r.x >> 17;
        int pos = atomicAdd(&s_cnt[dl], 1);
        er[beg + s_excl[dl] + pos] = make_int2(r.x & 0x1FFFF, r.y);
    }
}

// ================= tf layers 1,2 (reads h) =================
__global__ __launch_bounds__(256) void k_tf(const float* __restrict__ h,
    const unsigned short* __restrict__ wt_l, const float* __restrict__ feff_l,
    const float* __restrict__ c0_l, float* __restrict__ ai, unsigned* __restrict__ packed)
{
    int t = threadIdx.x;
    int wv = t >> 6, l = t & 63;
    int r16 = l & 15, quad = l >> 4;
    int n0 = blockIdx.x * 64 + wv * 16;
    int na = n0 + r16; if (na >= NN) na = NN - 1;
    const float* hp = h + (size_t)na * 64 + quad * 8;
    bf16x8 a[2];
    #pragma unroll
    for (int ks = 0; ks < 2; ks++) {
        f32x4 lo = *(const f32x4*)(hp + ks * 32);
        f32x4 hi = *(const f32x4*)(hp + ks * 32 + 4);
        bf16x8 tt;
        tt[0] = (short)f2bf(lo[0]); tt[1] = (short)f2bf(lo[1]);
        tt[2] = (short)f2bf(lo[2]); tt[3] = (short)f2bf(lo[3]);
        tt[4] = (short)f2bf(hi[0]); tt[5] = (short)f2bf(hi[1]);
        tt[6] = (short)f2bf(hi[2]); tt[7] = (short)f2bf(hi[3]);
        a[ks] = tt;
    }
    tf_core(a, wt_l, feff_l, c0_l, ai, packed, n0, r16, quad);
}

// ================= fused softmax-attention aggregate, unroll-16, 32-bit gather idx =================
#define EDGE_STEP(q, dacc, sacc) { \
    float aa = fmaf(__int_as_float(e[q].y), uc, base + __uint_as_float(p[q] & 0xffff0000u)); \
    aa = fmaxf(aa, NEG * aa); \
    float xx = EXP2(aa); \
    dacc += xx; sacc = fmaf(xx, __uint_as_float(p[q] << 16), sacc); }

__global__ __launch_bounds__(256) void k_edge(const unsigned* __restrict__ packed_r,
    const float* __restrict__ ai, const int* __restrict__ row_ptr,
    const int2* __restrict__ er, const float* __restrict__ u_l,
    float* __restrict__ hout)
{
    int w = threadIdx.x >> 6, c = threadIdx.x & 63;
    int n = blockIdx.x * 4 + w;                   // grid exact NN/4
    int beg = row_ptr[n], end = row_ptr[n + 1];
    float base = ai[n * 64 + c];                  // c0 folded in (log2 domain)
    float uc = u_l[c];
    float d0 = 0.f, d1 = 0.f, s0 = 0.f, s1 = 0.f;
    int k = beg;
    for (; k + 16 <= end; k += 16) {
        int2 e[16]; unsigned p[16];
        #pragma unroll
        for (int q = 0; q < 16; q++) e[q] = er[k + q];
        #pragma unroll
        for (int q = 0; q < 16; q++) p[q] = packed_r[(unsigned)((e[q].x << 6) | c)];
        #pragma unroll
        for (int q = 0; q < 16; q++) {
            if (q & 1) EDGE_STEP(q, d1, s1) else EDGE_STEP(q, d0, s0)
        }
    }
    for (; k + 8 <= end; k += 8) {
        int2 e[8]; unsigned p[8];
        #pragma unroll
        for (int q = 0; q < 8; q++) e[q] = er[k + q];
        #pragma unroll
        for (int q = 0; q < 8; q++) p[q] = packed_r[(unsigned)((e[q].x << 6) | c)];
        #pragma unroll
        for (int q = 0; q < 8; q++) {
            if (q & 1) EDGE_STEP(q, d1, s1) else EDGE_STEP(q, d0, s0)
        }
    }
    for (; k + 4 <= end; k += 4) {
        int2 e[4]; unsigned p[4];
        #pragma unroll
        for (int q = 0; q < 4; q++) e[q] = er[k + q];
        #pragma unroll
        for (int q = 0; q < 4; q++) p[q] = packed_r[(unsigned)((e[q].x << 6) | c)];
        #pragma unroll
        for (int q = 0; q < 4; q++) {
            if (q & 1) EDGE_STEP(q, d1, s1) else EDGE_STEP(q, d0, s0)
        }
    }
    for (; k < end; k++) {
        int2 e[1]; unsigned p[1];
        e[0] = er[k];
        p[0] = packed_r[(unsigned)((e[0].x << 6) | c)];
        EDGE_STEP(0, d0, s0)
    }
    hout[n * 64 + c] = (s0 + s1) / (d0 + d1 + 1e-16f);
}

// ---------------- launch ----------------
extern "C" void kernel_launch(void* const* d_in, const int* in_sizes, int n_in,
                              void* d_out, int out_size, void* d_ws, size_t ws_size,
                              hipStream_t stream)
{
    const float* x    = (const float*)d_in[0];
    const float* ea   = (const float*)d_in[1];
    const int*   ei   = (const int*)d_in[2];
    const float* fnw  = (const float*)d_in[3];
    const float* fnb  = (const float*)d_in[4];
    const float* few  = (const float*)d_in[5];
    const float* feb  = (const float*)d_in[6];
    const float* gmm  = (const float*)d_in[7];
    const float* beta = (const float*)d_in[8];
    const float* fcw  = (const float*)d_in[9];
    const float* fcb  = (const float*)d_in[10];
    const float* aw   = (const float*)d_in[11];
    const float* ab   = (const float*)d_in[12];
    float* out = (float*)d_out;

    char* ws = (char*)d_ws;
    size_t off = 0;
    auto alloc = [&](size_t bytes) -> void* {
        void* p = ws + off;
        off += (bytes + 255) / 256 * 256;
        return p;
    };
    float*    h       = (float*)   alloc((size_t)NN * 64 * 4);
    float*    ai      = (float*)   alloc((size_t)NN * 64 * 4);
    unsigned* packed  = (unsigned*)alloc((size_t)NN * 64 * 4);
    int2*     er      = (int2*)    alloc((size_t)NE * 8);
    int2*     brec    = (int2*)    alloc((size_t)NE * 8);
    int*      row_ptr = (int*)     alloc((size_t)(NN + 1) * 4);
    int*      counts  = (int*)     alloc((size_t)NB * NWG * 4);
    int*      bbase   = (int*)     alloc((NB + 1) * 4);
    float*    mom     = (float*)   alloc(12 * 4);
    float*    uvec    = (float*)   alloc(192 * 4);
    float*    c0vec   = (float*)   alloc(192 * 4);
    float*    feff    = (float*)   alloc(192 * 4);
    unsigned short* wt = (unsigned short*)alloc((size_t)LAYERS * 192 * 64 * 2);

    (void)hipMemsetAsync(mom, 0, 12 * 4, stream);

    // L1: bucket histogram + x moments
    k_front<<<NWG + MOMB, 256, 0, stream>>>(ei, counts, x, mom);
    // L2: params + bucket scan + weight prep (attention path pre-scaled by log2e)
    k_mid<<<2 + 144, 256, 0, stream>>>(mom, fnw, fnb, gmm, beta, few, feb, aw, ab,
                                       fcb, fcw, counts, bbase, row_ptr,
                                       uvec, c0vec, feff, wt);
    // L3: bucket write + tf layer 0 -> ai, packed
    k_l3<<<NWG + TFB, 256, 0, stream>>>(ei, ea, counts, brec, x, fnw, fnb,
                                        wt, feff, c0vec, ai, packed);
    // L4: csr finalize
    k_csr<<<NB, 256, 0, stream>>>(brec, bbase, row_ptr, er);
    // L5..: edge / tf chain
    k_edge<<<NN / 4, 256, 0, stream>>>(packed, ai, row_ptr, er, uvec, h);
    k_tf<<<TFB, 256, 0, stream>>>(h, wt + (size_t)192 * 64, feff + 64, c0vec + 64, ai, packed);
    k_edge<<<NN / 4, 256, 0, stream>>>(packed, ai, row_ptr, er, uvec + 64, h);
    k_tf<<<TFB, 256, 0, stream>>>(h, wt + (size_t)2 * 192 * 64, feff + 128, c0vec + 128, ai, packed);
    k_edge<<<NN / 4, 256, 0, stream>>>(packed, ai, row_ptr, er, uvec + 128, out);
    (void)in_sizes; (void)n_in; (void)out_size; (void)ws_size;
}